// Round 13
// baseline (96.528 us; speedup 1.0000x reference)
//
#include <hip/hip_runtime.h>

// KANConv2d, round 13: full-substep register prefetch (R12 taken to the limit).
// out[b,o,h,w] = sum_{c,tap,j} Wc[o,c,tap,j] * f_j(xp[b,c,h+dh,w+dw])
// f = {silu(v), B_0..B_6(v)} cardinal cubic B-splines (t = 2v+5), 8 bf16/granule.
// Structure: grid 256 (b x hquad), 1 block/CU, 8 waves (wave = 64o x 64w x 1h, 2x2 frags).
//   A: global_load_lds DMA, triple-buffered At[dh], issued 2 substeps ahead.
//   ALL 24 fragments of substep s+1 are ds_read during substep s into persistent
//   regs fA/fB -> each MFMA cluster is 100% reg-fed, issues right after its barrier;
//   reads for s+1 and DMA for s+2 hide under the cluster. At cb boundaries fB is
//   refilled post-barrier (FEATW publishes at that barrier). vmcnt counts per R12.

#define BB 16
#define CC 64
#define HH 64
#define WW 64
#define OO 128

typedef __bf16 bf16x8 __attribute__((ext_vector_type(8)));
typedef float f32x16 __attribute__((ext_vector_type(16)));

__device__ __forceinline__ bf16x8 as_bf16x8(uint4 v) { return __builtin_bit_cast(bf16x8, v); }
__device__ __forceinline__ unsigned bfb(float f) {
    return (unsigned)__builtin_bit_cast(unsigned short, (__bf16)f);
}

// 8-feature granule {silu(v), B_0(v)..B_6(v)} packed as 8 bf16 via 128-bit shift scatter.
__device__ __forceinline__ uint4 feat_granule(float v) {
    const float silu = __fdividef(v, 1.f + __expf(-v));
    const float t  = fmaf(2.f, v, 5.f);
    const float fi = floorf(t);
    const float u  = t - fi;
    const float um = 1.f - u;
    const float u2 = u * u, u3 = u2 * u;
    const float k0 = um * um * um * (1.f / 6.f);
    const float k1 = fmaf(0.5f, u3, (2.f / 3.f) - u2);
    const float k2 = fmaf(-0.5f, u3, fmaf(0.5f, u2, fmaf(0.5f, u, 1.f / 6.f)));
    const float k3 = u3 * (1.f / 6.f);
    const bool valid = (t >= 0.f) && (t < 10.f);
    unsigned long long K =
        (unsigned long long)bfb(k0)         |
        ((unsigned long long)bfb(k1) << 16) |
        ((unsigned long long)bfb(k2) << 32) |
        ((unsigned long long)bfb(k3) << 48);
    if (!valid) K = 0ull;
    const int ic = min(max((int)fi, -2), 9);
    const int sh = 16 * ic - 32;            // [-64, 112]
    unsigned __int128 P = (sh >= 0) ? ((unsigned __int128)K << sh)
                                    : ((unsigned __int128)K >> (-sh));
    uint4 pk = __builtin_bit_cast(uint4, P);
    pk.x = (pk.x & 0xFFFF0000u) | bfb(silu);
    return pk;
}

// ---------------- weight prep: Wb[cb][tap][c_l][o][j] bf16, j contiguous ----------------
__global__ __launch_bounds__(256) void kan_wprep(
    const float* __restrict__ beta, const float* __restrict__ spl,
    const float* __restrict__ cf, uint4* __restrict__ wb)
{
    int t = blockIdx.x * 256 + threadIdx.x;      // 73728 = (o, c, tap)
    int tap = t % 9;
    int c   = (t / 9) & 63;
    int o   = t / 576;
    int base = (o * CC + c) * 9 + tap;
    float bv = beta[base];
    float sv = spl[base];
    float f[8];
    f[0] = bv;
    #pragma unroll
    for (int s = 0; s < 7; ++s)
        f[1 + s] = sv * cf[((s * OO + o) * CC + c) * 9 + tap];
    uint4 pk;
    pk.x = bfb(f[0]) | (bfb(f[1]) << 16);
    pk.y = bfb(f[2]) | (bfb(f[3]) << 16);
    pk.z = bfb(f[4]) | (bfb(f[5]) << 16);
    pk.w = bfb(f[6]) | (bfb(f[7]) << 16);
    int cb = c >> 2, cl = c & 3;
    wb[((cb * 9 + tap) * 4 + cl) * OO + o] = pk;
}

// ---------------- main implicit GEMM ----------------
__global__ __launch_bounds__(512, 2) void kan_mfma10(
    const float* __restrict__ x, const uint4* __restrict__ wb,
    float* __restrict__ out)
{
    // B/features: [buf][(cl*6 + row)*66 + col], 1584 granules/buf
    __shared__ uint4 Bt[2][1584];
    // A/weights substep tile: TRIPLE buffered, At[dh] holds (cb, dh)
    __shared__ uint4 At[3][1536];

    const int tid  = threadIdx.x;
    const int blk  = blockIdx.x;
    const int hq   = blk & 15;
    const int b    = blk >> 4;
    const int h0   = hq << 2;          // output rows h0..h0+3; input rows h0-1..h0+4

    const int ww    = tid >> 6;        // wave 0..7
    const int lane  = tid & 63;
    const int lo    = lane & 31;
    const int hi    = lane >> 5;
    const int ohalf = ww & 1;
    const int hrow  = ww >> 1;         // 0..3

    f32x16 acc[2][2] = {};             // [oi][wi]
    float xv[4];
    uint4 fA[3][2][2], fB[3][2][2];    // persistent substep fragments [tl][kh][oi/wi]

    // ---- x loads for channel-block cbi: 1584 granule-pixels (4cl x 6rows x 66) ----
    #define XLOAD(cbi) do {                                                   \
        _Pragma("unroll")                                                     \
        for (int k = 0; k < 4; ++k) {                                         \
            const int g = tid + k * 512;                                      \
            float v = 0.f;                                                    \
            if (g < 1584) {                                                   \
                const int cl_ = g / 396;                                      \
                const int r_  = (g % 396) / 66;                               \
                const int co_ = g % 66;                                       \
                const int hx  = h0 - 1 + r_;                                  \
                const int wx  = co_ - 1;                                      \
                if ((unsigned)hx < 64u && (unsigned)wx < 64u)                 \
                    v = x[((b * CC + (cbi) * 4 + cl_) * HH + hx) * WW + wx];  \
            }                                                                 \
            xv[k] = v;                                                        \
        }                                                                     \
    } while (0)

    // ---- feature compute + LDS write into Bt[bufi] ----
    #define FEATW(bufi) do {                                                  \
        _Pragma("unroll")                                                     \
        for (int k = 0; k < 4; ++k) {                                         \
            const int g = tid + k * 512;                                      \
            if (g < 1584) Bt[bufi][g] = feat_granule(xv[k]);                  \
        }                                                                     \
    } while (0)

    // ---- DMA one A substep slice (cb1, dh1) into At[bufi]: 24 x 1KB, 3/wave ----
    #define ADMA(bufi, cb1, dh1) do {                                         \
        const uint4* asrc = wb + ((cb1) * 4608 + (dh1) * 1536)                \
                            + ww * 192 + lane;                                \
        _Pragma("unroll")                                                     \
        for (int i = 0; i < 3; ++i)                                           \
            __builtin_amdgcn_global_load_lds(                                 \
                (const __attribute__((address_space(1))) void*)(asrc + i*64), \
                (__attribute__((address_space(3))) void*)                     \
                    &At[bufi][ww * 192 + i * 64],                             \
                16, 0, 0);                                                    \
    } while (0)

    // ---- pre-read ALL A fragments of one substep from slot Ab ----
    #define PRE_A(Ab) do {                                                    \
        _Pragma("unroll")                                                     \
        for (int tl = 0; tl < 3; ++tl)                                        \
            _Pragma("unroll")                                                 \
            for (int kh = 0; kh < 2; ++kh) {                                  \
                const int arow = (tl * 4 + kh * 2 + hi) * 128                 \
                                 + ohalf * 64 + lo;                           \
                fA[tl][kh][0] = (Ab)[arow];                                   \
                fA[tl][kh][1] = (Ab)[arow + 32];                              \
            }                                                                 \
    } while (0)

    // ---- pre-read ALL B fragments of one substep (rows for dh = dhv) ----
    #define PRE_B(Bb, dhv) do {                                               \
        _Pragma("unroll")                                                     \
        for (int tl = 0; tl < 3; ++tl)                                        \
            _Pragma("unroll")                                                 \
            for (int kh = 0; kh < 2; ++kh) {                                  \
                const int brow = ((kh * 2 + hi) * 6 + hrow + (dhv)) * 66      \
                                 + tl + lo;                                   \
                fB[tl][kh][0] = (Bb)[brow];                                   \
                fB[tl][kh][1] = (Bb)[brow + 32];                              \
            }                                                                 \
    } while (0)

    // ---- the substep's 24 MFMAs, fully register-fed ----
    #define MFMA_ALL() do {                                                   \
        __builtin_amdgcn_s_setprio(1);                                        \
        _Pragma("unroll")                                                     \
        for (int tl = 0; tl < 3; ++tl)                                        \
            _Pragma("unroll")                                                 \
            for (int oi = 0; oi < 2; ++oi)                                    \
                _Pragma("unroll")                                             \
                for (int wi = 0; wi < 2; ++wi)                                \
                    _Pragma("unroll")                                         \
                    for (int kh = 0; kh < 2; ++kh)                            \
                        acc[oi][wi] = __builtin_amdgcn_mfma_f32_32x32x16_bf16(\
                            as_bf16x8(fA[tl][kh][oi]),                        \
                            as_bf16x8(fB[tl][kh][wi]),                        \
                            acc[oi][wi], 0, 0, 0);                            \
        __builtin_amdgcn_s_setprio(0);                                        \
    } while (0)

    // prologue: Bt[0] <- features(cb0); At[0] <- (0,0); At[1] <- (0,1); drain; pre-read A
    XLOAD(0);
    ADMA(0, 0, 0);
    ADMA(1, 0, 1);
    FEATW(0);
    asm volatile("s_waitcnt vmcnt(0) lgkmcnt(0)" ::: "memory");
    __builtin_amdgcn_s_barrier();
    __builtin_amdgcn_sched_barrier(0);
    PRE_A(At[0]);

    #pragma unroll 1
    for (int cb = 0; cb < 16; ++cb) {
        #pragma unroll
        for (int dh = 0; dh < 3; ++dh) {
            // substep s = cb*3+dh consumes fA/fB (preloaded), reads At[dh]/Bt[cb&1]
            if (dh == 0) PRE_B(Bt[cb & 1], 0);   // deferred across cb boundary (FEATW)

            MFMA_ALL();

            // ---- issue DMA for substep s+2 / x loads for next cb ----
            if (dh == 0) {
                ADMA(2, cb, 2);
                __builtin_amdgcn_sched_barrier(0);   // pin ADMA older than XLOAD
                if (cb < 15) XLOAD(cb + 1);
            } else if (dh == 1) {
                if (cb < 15) ADMA(0, cb + 1, 0);
            } else {
                if (cb < 15) ADMA(1, cb + 1, 1);
            }

            // ---- pre-read ALL fragments for substep s+1 ----
            if (!(cb == 15 && dh == 2)) {
                if (dh == 0)      PRE_A(At[1]);
                else if (dh == 1) PRE_A(At[2]);
                else              PRE_A(At[0]);
                if (dh < 2) PRE_B(Bt[cb & 1], dh + 1);  // same Bt buffer within cb
            }

            if (dh == 2 && cb < 15) FEATW((cb + 1) & 1);  // publish next-cb features

            // ---- raw barrier with counted waits (R12-proven counts) ----
            if (!(cb == 15 && dh == 2)) {
                if (dh == 0) {
                    if (cb < 15) asm volatile("s_waitcnt vmcnt(4)" ::: "memory");
                    else         asm volatile("s_waitcnt vmcnt(0)" ::: "memory");
                } else if (dh == 1) {
                    asm volatile("s_waitcnt vmcnt(0)" ::: "memory");
                } else {
                    asm volatile("s_waitcnt vmcnt(0) lgkmcnt(0)" ::: "memory");
                }
                __builtin_amdgcn_s_barrier();
                __builtin_amdgcn_sched_barrier(0);
            }
        }
    }

    // ---- store: w-coalesced dword stores ----
    const int h = h0 + hrow;
    #pragma unroll
    for (int oi = 0; oi < 2; ++oi)
        #pragma unroll
        for (int wi = 0; wi < 2; ++wi) {
            const int wc = wi * 32 + lo;
            #pragma unroll
            for (int r = 0; r < 16; ++r) {
                const int o = ohalf * 64 + oi * 32 + (r & 3) + ((r >> 2) << 3) + (hi << 2);
                out[((b * OO + o) * HH + h) * WW + wc] = acc[oi][wi][r];
            }
        }
}

extern "C" void kernel_launch(void* const* d_in, const int* in_sizes, int n_in,
                              void* d_out, int out_size, void* d_ws, size_t ws_size,
                              hipStream_t stream) {
    const float* x    = (const float*)d_in[0];
    const float* beta = (const float*)d_in[1];
    const float* spl  = (const float*)d_in[2];
    const float* cf   = (const float*)d_in[3];
    float* out = (float*)d_out;
    uint4* wb  = (uint4*)d_ws;          // 73728 granules = 1.18 MB

    kan_wprep<<<288, 256, 0, stream>>>(beta, spl, cf, wb);
    kan_mfma10<<<BB * 16, 512, 0, stream>>>(x, wb, out);
}

// Round 15
// 93.784 us; speedup vs baseline: 1.0293x; 1.0293x over previous
//
#include <hip/hip_runtime.h>

// KANConv2d, round 15: R14 (A streamed L2->registers, 1 barrier/cb) with the
// A-address bug fixed: granule index = ((cb*9+tap)*4 + kh*2 + hi)*128 + ohalf*64 + lo.
// R14 had (hi*2)*128 in the base (should be hi*128) -> hi=1 lanes read wrong cl.
//
// out[b,o,h,w] = sum_{c,tap,j} Wc[o,c,tap,j] * f_j(xp[b,c,h+dh,w+dw])
// f = {silu(v), B_0..B_6(v)} cardinal cubic B-splines (t = 2v+5), 8 bf16/granule.
// Structure: grid 256 (b x hquad), 1 block/CU, 8 waves (wave = 64o x 64w x 1h, 2x2 frags).
//   A (weights): per-wave global loads (16B/lane coalesced) from L2-resident 1.18MB
//     packed tensor -- LDS port carries only B reads + FEATW writes; 1 barrier/cb.
//   B (features): computed in-kernel, double-buffered in LDS per cb.

#define BB 16
#define CC 64
#define HH 64
#define WW 64
#define OO 128

typedef __bf16 bf16x8 __attribute__((ext_vector_type(8)));
typedef float f32x16 __attribute__((ext_vector_type(16)));

__device__ __forceinline__ bf16x8 as_bf16x8(uint4 v) { return __builtin_bit_cast(bf16x8, v); }
__device__ __forceinline__ unsigned bfb(float f) {
    return (unsigned)__builtin_bit_cast(unsigned short, (__bf16)f);
}

// 8-feature granule {silu(v), B_0(v)..B_6(v)} packed as 8 bf16 via 128-bit shift scatter.
__device__ __forceinline__ uint4 feat_granule(float v) {
    const float silu = __fdividef(v, 1.f + __expf(-v));
    const float t  = fmaf(2.f, v, 5.f);
    const float fi = floorf(t);
    const float u  = t - fi;
    const float um = 1.f - u;
    const float u2 = u * u, u3 = u2 * u;
    const float k0 = um * um * um * (1.f / 6.f);
    const float k1 = fmaf(0.5f, u3, (2.f / 3.f) - u2);
    const float k2 = fmaf(-0.5f, u3, fmaf(0.5f, u2, fmaf(0.5f, u, 1.f / 6.f)));
    const float k3 = u3 * (1.f / 6.f);
    const bool valid = (t >= 0.f) && (t < 10.f);
    unsigned long long K =
        (unsigned long long)bfb(k0)         |
        ((unsigned long long)bfb(k1) << 16) |
        ((unsigned long long)bfb(k2) << 32) |
        ((unsigned long long)bfb(k3) << 48);
    if (!valid) K = 0ull;
    const int ic = min(max((int)fi, -2), 9);
    const int sh = 16 * ic - 32;            // [-64, 112]
    unsigned __int128 P = (sh >= 0) ? ((unsigned __int128)K << sh)
                                    : ((unsigned __int128)K >> (-sh));
    uint4 pk = __builtin_bit_cast(uint4, P);
    pk.x = (pk.x & 0xFFFF0000u) | bfb(silu);
    return pk;
}

// ---------------- weight prep: Wb[cb][tap][c_l][o][j] bf16, j contiguous ----------------
__global__ __launch_bounds__(256) void kan_wprep(
    const float* __restrict__ beta, const float* __restrict__ spl,
    const float* __restrict__ cf, uint4* __restrict__ wb)
{
    int t = blockIdx.x * 256 + threadIdx.x;      // 73728 = (o, c, tap)
    int tap = t % 9;
    int c   = (t / 9) & 63;
    int o   = t / 576;
    int base = (o * CC + c) * 9 + tap;
    float bv = beta[base];
    float sv = spl[base];
    float f[8];
    f[0] = bv;
    #pragma unroll
    for (int s = 0; s < 7; ++s)
        f[1 + s] = sv * cf[((s * OO + o) * CC + c) * 9 + tap];
    uint4 pk;
    pk.x = bfb(f[0]) | (bfb(f[1]) << 16);
    pk.y = bfb(f[2]) | (bfb(f[3]) << 16);
    pk.z = bfb(f[4]) | (bfb(f[5]) << 16);
    pk.w = bfb(f[6]) | (bfb(f[7]) << 16);
    int cb = c >> 2, cl = c & 3;
    wb[((cb * 9 + tap) * 4 + cl) * OO + o] = pk;
}

// ---------------- main implicit GEMM ----------------
__global__ __launch_bounds__(512, 2) void kan_mfma12(
    const float* __restrict__ x, const uint4* __restrict__ wb,
    float* __restrict__ out)
{
    // B/features: [buf][(cl*6 + row)*66 + col], 1584 granules/buf  (only LDS user)
    __shared__ uint4 Bt[2][1584];

    const int tid  = threadIdx.x;
    const int blk  = blockIdx.x;
    const int hq   = blk & 15;
    const int b    = blk >> 4;
    const int h0   = hq << 2;          // output rows h0..h0+3; input rows h0-1..h0+4

    const int ww    = tid >> 6;        // wave 0..7
    const int lane  = tid & 63;
    const int lo    = lane & 31;
    const int hi    = lane >> 5;
    const int ohalf = ww & 1;
    const int hrow  = ww >> 1;         // 0..3

    f32x16 acc[2][2] = {};             // [oi][wi]
    float xv[4];

    // per-wave/lane A base: granule = ((cb*9+tap)*4 + kh*2 + hi)*128 + ohalf*64 + oi*32 + lo
    // base carries the hi*128 + ohalf*64 + lo part; (cb,tap,kh,oi) added as offsets.
    const uint4* wvbase = wb + hi * OO + ohalf * 64 + lo;

    // ---- x loads for channel-block cbi: 1584 granule-pixels (4cl x 6rows x 66) ----
    #define XLOAD(cbi) do {                                                   \
        _Pragma("unroll")                                                     \
        for (int k = 0; k < 4; ++k) {                                         \
            const int g = tid + k * 512;                                      \
            float v = 0.f;                                                    \
            if (g < 1584) {                                                   \
                const int cl_ = g / 396;                                      \
                const int r_  = (g % 396) / 66;                               \
                const int co_ = g % 66;                                       \
                const int hx  = h0 - 1 + r_;                                  \
                const int wx  = co_ - 1;                                      \
                if ((unsigned)hx < 64u && (unsigned)wx < 64u)                 \
                    v = x[((b * CC + (cbi) * 4 + cl_) * HH + hx) * WW + wx];  \
            }                                                                 \
            xv[k] = v;                                                        \
        }                                                                     \
    } while (0)

    // ---- feature compute + LDS write into Bt[bufi] ----
    #define FEATW(bufi) do {                                                  \
        _Pragma("unroll")                                                     \
        for (int k = 0; k < 4; ++k) {                                         \
            const int g = tid + k * 512;                                      \
            if (g < 1584) Bt[bufi][g] = feat_granule(xv[k]);                  \
        }                                                                     \
    } while (0)

    // prologue: Bt[0] <- features(cb0)
    XLOAD(0);
    FEATW(0);
    asm volatile("s_waitcnt lgkmcnt(0)" ::: "memory");
    __builtin_amdgcn_s_barrier();

    #pragma unroll 1
    for (int cb = 0; cb < 16; ++cb) {
        if (cb < 15) XLOAD(cb + 1);            // issue early; consumed by FEATW below

        const uint4* Bb  = Bt[cb & 1];
        const uint4* wcb = wvbase + (size_t)cb * 4608;   // cb block = 9*4*128 granules

        #pragma unroll
        for (int dh = 0; dh < 3; ++dh) {
            #pragma unroll
            for (int tl = 0; tl < 3; ++tl) {
                const int tap = dh * 3 + tl;

                // A fragments: global (L2-resident), 16B/lane coalesced
                uint4 a[2][2];                  // [kh][oi]
                #pragma unroll
                for (int kh = 0; kh < 2; ++kh) {
                    const uint4* wr = wcb + (tap * 4 + kh * 2) * OO;
                    a[kh][0] = wr[0];
                    a[kh][1] = wr[32];
                }

                // B fragments from LDS
                bf16x8 Bf[2][2];                // [kh][wi]
                #pragma unroll
                for (int kh = 0; kh < 2; ++kh) {
                    const int brow = ((kh * 2 + hi) * 6 + hrow + dh) * 66 + tl + lo;
                    Bf[kh][0] = as_bf16x8(Bb[brow]);
                    Bf[kh][1] = as_bf16x8(Bb[brow + 32]);
                }

                __builtin_amdgcn_s_setprio(1);
                #pragma unroll
                for (int oi = 0; oi < 2; ++oi)
                    #pragma unroll
                    for (int wi = 0; wi < 2; ++wi)
                        #pragma unroll
                        for (int kh = 0; kh < 2; ++kh)
                            acc[oi][wi] = __builtin_amdgcn_mfma_f32_32x32x16_bf16(
                                as_bf16x8(a[kh][oi]), Bf[kh][wi],
                                acc[oi][wi], 0, 0, 0);
                __builtin_amdgcn_s_setprio(0);
            }
        }

        // publish next cb's features; the ONLY barrier in the loop
        if (cb < 15) {
            FEATW((cb + 1) & 1);
            asm volatile("s_waitcnt lgkmcnt(0)" ::: "memory");
            __builtin_amdgcn_s_barrier();
        }
    }

    // ---- store: w-coalesced dword stores ----
    const int h = h0 + hrow;
    #pragma unroll
    for (int oi = 0; oi < 2; ++oi)
        #pragma unroll
        for (int wi = 0; wi < 2; ++wi) {
            const int wc = wi * 32 + lo;
            #pragma unroll
            for (int r = 0; r < 16; ++r) {
                const int o = ohalf * 64 + oi * 32 + (r & 3) + ((r >> 2) << 3) + (hi << 2);
                out[((b * OO + o) * HH + h) * WW + wc] = acc[oi][wi][r];
            }
        }
}

extern "C" void kernel_launch(void* const* d_in, const int* in_sizes, int n_in,
                              void* d_out, int out_size, void* d_ws, size_t ws_size,
                              hipStream_t stream) {
    const float* x    = (const float*)d_in[0];
    const float* beta = (const float*)d_in[1];
    const float* spl  = (const float*)d_in[2];
    const float* cf   = (const float*)d_in[3];
    float* out = (float*)d_out;
    uint4* wb  = (uint4*)d_ws;          // 73728 granules = 1.18 MB

    kan_wprep<<<288, 256, 0, stream>>>(beta, spl, cf, wb);
    kan_mfma12<<<BB * 16, 512, 0, stream>>>(x, wb, out);
}

// Round 16
// 90.663 us; speedup vs baseline: 1.0647x; 1.0344x over previous
//
#include <hip/hip_runtime.h>

// KANConv2d, round 16: R15 (A streamed L2->regs, 1 barrier/cb) with the pipeline
// actually built: NO setprio in the loop (it fenced VMEM hoisting -> VGPR=68,
// exposed L2 latency), explicit depth-2 A prefetch via 3 rotating reg sets
// (9 taps % 3 == 0 -> set alignment survives the runtime cb loop; all indices
// compile-time after unroll).
//
// out[b,o,h,w] = sum_{c,tap,j} Wc[o,c,tap,j] * f_j(xp[b,c,h+dh,w+dw])
// f = {silu(v), B_0..B_6(v)} cardinal cubic B-splines (t = 2v+5), 8 bf16/granule.
// Structure: grid 256 (b x hquad), 1 block/CU, 8 waves (wave = 64o x 64w x 1h, 2x2 frags).
//   A granule = ((cb*9+tap)*4 + kh*2 + hi)*128 + ohalf*64 + oi*32 + lo  (R15-verified).
//   B (features) computed in-kernel, double-buffered in LDS; 1 lgkm+barrier per cb.

#define BB 16
#define CC 64
#define HH 64
#define WW 64
#define OO 128

typedef __bf16 bf16x8 __attribute__((ext_vector_type(8)));
typedef float f32x16 __attribute__((ext_vector_type(16)));

__device__ __forceinline__ bf16x8 as_bf16x8(uint4 v) { return __builtin_bit_cast(bf16x8, v); }
__device__ __forceinline__ unsigned bfb(float f) {
    return (unsigned)__builtin_bit_cast(unsigned short, (__bf16)f);
}

// 8-feature granule {silu(v), B_0(v)..B_6(v)} packed as 8 bf16 via 128-bit shift scatter.
__device__ __forceinline__ uint4 feat_granule(float v) {
    const float silu = __fdividef(v, 1.f + __expf(-v));
    const float t  = fmaf(2.f, v, 5.f);
    const float fi = floorf(t);
    const float u  = t - fi;
    const float um = 1.f - u;
    const float u2 = u * u, u3 = u2 * u;
    const float k0 = um * um * um * (1.f / 6.f);
    const float k1 = fmaf(0.5f, u3, (2.f / 3.f) - u2);
    const float k2 = fmaf(-0.5f, u3, fmaf(0.5f, u2, fmaf(0.5f, u, 1.f / 6.f)));
    const float k3 = u3 * (1.f / 6.f);
    const bool valid = (t >= 0.f) && (t < 10.f);
    unsigned long long K =
        (unsigned long long)bfb(k0)         |
        ((unsigned long long)bfb(k1) << 16) |
        ((unsigned long long)bfb(k2) << 32) |
        ((unsigned long long)bfb(k3) << 48);
    if (!valid) K = 0ull;
    const int ic = min(max((int)fi, -2), 9);
    const int sh = 16 * ic - 32;            // [-64, 112]
    unsigned __int128 P = (sh >= 0) ? ((unsigned __int128)K << sh)
                                    : ((unsigned __int128)K >> (-sh));
    uint4 pk = __builtin_bit_cast(uint4, P);
    pk.x = (pk.x & 0xFFFF0000u) | bfb(silu);
    return pk;
}

// ---------------- weight prep: Wb[cb][tap][c_l][o][j] bf16, j contiguous ----------------
__global__ __launch_bounds__(256) void kan_wprep(
    const float* __restrict__ beta, const float* __restrict__ spl,
    const float* __restrict__ cf, uint4* __restrict__ wb)
{
    int t = blockIdx.x * 256 + threadIdx.x;      // 73728 = (o, c, tap)
    int tap = t % 9;
    int c   = (t / 9) & 63;
    int o   = t / 576;
    int base = (o * CC + c) * 9 + tap;
    float bv = beta[base];
    float sv = spl[base];
    float f[8];
    f[0] = bv;
    #pragma unroll
    for (int s = 0; s < 7; ++s)
        f[1 + s] = sv * cf[((s * OO + o) * CC + c) * 9 + tap];
    uint4 pk;
    pk.x = bfb(f[0]) | (bfb(f[1]) << 16);
    pk.y = bfb(f[2]) | (bfb(f[3]) << 16);
    pk.z = bfb(f[4]) | (bfb(f[5]) << 16);
    pk.w = bfb(f[6]) | (bfb(f[7]) << 16);
    int cb = c >> 2, cl = c & 3;
    wb[((cb * 9 + tap) * 4 + cl) * OO + o] = pk;
}

// ---------------- main implicit GEMM ----------------
__global__ __launch_bounds__(512, 2) void kan_mfma13(
    const float* __restrict__ x, const uint4* __restrict__ wb,
    float* __restrict__ out)
{
    // B/features: [buf][(cl*6 + row)*66 + col], 1584 granules/buf  (only LDS user)
    __shared__ uint4 Bt[2][1584];

    const int tid  = threadIdx.x;
    const int blk  = blockIdx.x;
    const int hq   = blk & 15;
    const int b    = blk >> 4;
    const int h0   = hq << 2;          // output rows h0..h0+3; input rows h0-1..h0+4

    const int ww    = tid >> 6;        // wave 0..7
    const int lane  = tid & 63;
    const int lo    = lane & 31;
    const int hi    = lane >> 5;
    const int ohalf = ww & 1;
    const int hrow  = ww >> 1;         // 0..3

    f32x16 acc[2][2] = {};             // [oi][wi]
    float xv[4];
    uint4 aS[3][2][2];                 // rotating A sets [set][kh][oi], indices static

    // per-lane A base: granule = ((cb*9+tap)*4 + kh*2 + hi)*128 + ohalf*64 + oi*32 + lo
    const uint4* wvbase = wb + hi * OO + ohalf * 64 + lo;

    // ---- x loads for channel-block cbi: 1584 granule-pixels (4cl x 6rows x 66) ----
    #define XLOAD(cbi) do {                                                   \
        _Pragma("unroll")                                                     \
        for (int k = 0; k < 4; ++k) {                                         \
            const int g = tid + k * 512;                                      \
            float v = 0.f;                                                    \
            if (g < 1584) {                                                   \
                const int cl_ = g / 396;                                      \
                const int r_  = (g % 396) / 66;                               \
                const int co_ = g % 66;                                       \
                const int hx  = h0 - 1 + r_;                                  \
                const int wx  = co_ - 1;                                      \
                if ((unsigned)hx < 64u && (unsigned)wx < 64u)                 \
                    v = x[((b * CC + (cbi) * 4 + cl_) * HH + hx) * WW + wx];  \
            }                                                                 \
            xv[k] = v;                                                        \
        }                                                                     \
    } while (0)

    // ---- feature compute + LDS write into Bt[bufi] ----
    #define FEATW(bufi) do {                                                  \
        _Pragma("unroll")                                                     \
        for (int k = 0; k < 4; ++k) {                                         \
            const int g = tid + k * 512;                                      \
            if (g < 1584) Bt[bufi][g] = feat_granule(xv[k]);                  \
        }                                                                     \
    } while (0)

    // ---- A fragments for tap `tapi` from base `bse` into set `dst` ----
    #define LOADA_G(dst, bse, tapi) do {                                      \
        const uint4* wr_ = (bse) + ((tapi) * 4) * OO;                         \
        dst[0][0] = wr_[0];                                                   \
        dst[0][1] = wr_[32];                                                  \
        dst[1][0] = wr_[2 * OO];                                              \
        dst[1][1] = wr_[2 * OO + 32];                                         \
    } while (0)

    // prologue: Bt[0] <- features(cb0); A sets 0,1 <- cb0 taps 0,1
    XLOAD(0);
    FEATW(0);
    LOADA_G(aS[0], wvbase, 0);
    LOADA_G(aS[1], wvbase, 1);
    asm volatile("s_waitcnt lgkmcnt(0)" ::: "memory");
    __builtin_amdgcn_s_barrier();

    #pragma unroll 1
    for (int cb = 0; cb < 16; ++cb) {
        if (cb < 15) XLOAD(cb + 1);            // issue early; consumed by FEATW below

        const uint4* Bb  = Bt[cb & 1];
        const uint4* wcb = wvbase + (size_t)cb * 4608;         // 9*4*128 granules/cb
        const uint4* wnx = wvbase + (size_t)(cb + 1) * 4608;

        #pragma unroll
        for (int tap = 0; tap < 9; ++tap) {
            const int dh = tap / 3;
            const int tl = tap % 3;

            // depth-2 A prefetch: tap+2 into set (tap+2)%3 (consumed 2 steps later).
            // 9 % 3 == 0 keeps set alignment across cb; loads ride over the barrier.
            if (tap < 7)           LOADA_G(aS[(tap + 2) % 3], wcb, tap + 2);
            else if (cb < 15)      LOADA_G(aS[(tap + 2) % 3], wnx, tap - 7);

            // B fragments from LDS
            bf16x8 Bf[2][2];                // [kh][wi]
            #pragma unroll
            for (int kh = 0; kh < 2; ++kh) {
                const int brow = ((kh * 2 + hi) * 6 + hrow + dh) * 66 + tl + lo;
                Bf[kh][0] = as_bf16x8(Bb[brow]);
                Bf[kh][1] = as_bf16x8(Bb[brow + 32]);
            }

            // 8 MFMAs, A from the rotating set (no setprio: it fenced the scheduler)
            #pragma unroll
            for (int oi = 0; oi < 2; ++oi)
                #pragma unroll
                for (int wi = 0; wi < 2; ++wi)
                    #pragma unroll
                    for (int kh = 0; kh < 2; ++kh)
                        acc[oi][wi] = __builtin_amdgcn_mfma_f32_32x32x16_bf16(
                            as_bf16x8(aS[tap % 3][kh][oi]), Bf[kh][wi],
                            acc[oi][wi], 0, 0, 0);
        }

        // publish next cb's features; the ONLY barrier in the loop
        if (cb < 15) {
            FEATW((cb + 1) & 1);
            asm volatile("s_waitcnt lgkmcnt(0)" ::: "memory");
            __builtin_amdgcn_s_barrier();
        }
    }

    // ---- store: w-coalesced dword stores ----
    const int h = h0 + hrow;
    #pragma unroll
    for (int oi = 0; oi < 2; ++oi)
        #pragma unroll
        for (int wi = 0; wi < 2; ++wi) {
            const int wc = wi * 32 + lo;
            #pragma unroll
            for (int r = 0; r < 16; ++r) {
                const int o = ohalf * 64 + oi * 32 + (r & 3) + ((r >> 2) << 3) + (hi << 2);
                out[((b * OO + o) * HH + h) * WW + wc] = acc[oi][wi][r];
            }
        }
}

extern "C" void kernel_launch(void* const* d_in, const int* in_sizes, int n_in,
                              void* d_out, int out_size, void* d_ws, size_t ws_size,
                              hipStream_t stream) {
    const float* x    = (const float*)d_in[0];
    const float* beta = (const float*)d_in[1];
    const float* spl  = (const float*)d_in[2];
    const float* cf   = (const float*)d_in[3];
    float* out = (float*)d_out;
    uint4* wb  = (uint4*)d_ws;          // 73728 granules = 1.18 MB

    kan_wprep<<<288, 256, 0, stream>>>(beta, spl, cf, wb);
    kan_mfma13<<<BB * 16, 512, 0, stream>>>(x, wb, out);
}

// Round 17
// 84.006 us; speedup vs baseline: 1.1491x; 1.0792x over previous
//
#include <hip/hip_runtime.h>

// KANConv2d, round 17: R12 (best, 82.7us) with the setprio fences removed.
// R15/R16 isolated on this kernel that s_setprio pairs around MFMA clusters act
// as a scheduler fence (VMEM/ds can't migrate across) — R12's compiler-scheduled
// interleave is the thing that has been winning; un-fence it. Single-variable change.
//
// out[b,o,h,w] = sum_{c,tap,j} Wc[o,c,tap,j] * f_j(xp[b,c,h+dh,w+dw])
// f = {silu(v), B_0..B_6(v)} cardinal cubic B-splines (t = 2v+5), 8 bf16/granule.
// Structure: grid 256 (b x hquad), 1 block/CU, 8 waves (wave = 64o x 64w x 1h, 2x2 frags).
//   A: global_load_lds DMA, triple-buffered At[dh], issued 2 substeps ahead.
//   tl0 fragments for substep s+1 ds_read at the END of substep s into persistent
//   regs pA/pB (cross-barrier pre-read, R12's proven +8us lever). vmcnt 4/0/0.

#define BB 16
#define CC 64
#define HH 64
#define WW 64
#define OO 128

typedef __bf16 bf16x8 __attribute__((ext_vector_type(8)));
typedef float f32x16 __attribute__((ext_vector_type(16)));

__device__ __forceinline__ bf16x8 as_bf16x8(uint4 v) { return __builtin_bit_cast(bf16x8, v); }
__device__ __forceinline__ unsigned bfb(float f) {
    return (unsigned)__builtin_bit_cast(unsigned short, (__bf16)f);
}

// 8-feature granule {silu(v), B_0(v)..B_6(v)} packed as 8 bf16 via 128-bit shift scatter.
__device__ __forceinline__ uint4 feat_granule(float v) {
    const float silu = __fdividef(v, 1.f + __expf(-v));
    const float t  = fmaf(2.f, v, 5.f);
    const float fi = floorf(t);
    const float u  = t - fi;
    const float um = 1.f - u;
    const float u2 = u * u, u3 = u2 * u;
    const float k0 = um * um * um * (1.f / 6.f);
    const float k1 = fmaf(0.5f, u3, (2.f / 3.f) - u2);
    const float k2 = fmaf(-0.5f, u3, fmaf(0.5f, u2, fmaf(0.5f, u, 1.f / 6.f)));
    const float k3 = u3 * (1.f / 6.f);
    const bool valid = (t >= 0.f) && (t < 10.f);
    unsigned long long K =
        (unsigned long long)bfb(k0)         |
        ((unsigned long long)bfb(k1) << 16) |
        ((unsigned long long)bfb(k2) << 32) |
        ((unsigned long long)bfb(k3) << 48);
    if (!valid) K = 0ull;
    const int ic = min(max((int)fi, -2), 9);
    const int sh = 16 * ic - 32;            // [-64, 112]
    unsigned __int128 P = (sh >= 0) ? ((unsigned __int128)K << sh)
                                    : ((unsigned __int128)K >> (-sh));
    uint4 pk = __builtin_bit_cast(uint4, P);
    pk.x = (pk.x & 0xFFFF0000u) | bfb(silu);
    return pk;
}

// ---------------- weight prep: Wb[cb][tap][c_l][o][j] bf16, j contiguous ----------------
__global__ __launch_bounds__(256) void kan_wprep(
    const float* __restrict__ beta, const float* __restrict__ spl,
    const float* __restrict__ cf, uint4* __restrict__ wb)
{
    int t = blockIdx.x * 256 + threadIdx.x;      // 73728 = (o, c, tap)
    int tap = t % 9;
    int c   = (t / 9) & 63;
    int o   = t / 576;
    int base = (o * CC + c) * 9 + tap;
    float bv = beta[base];
    float sv = spl[base];
    float f[8];
    f[0] = bv;
    #pragma unroll
    for (int s = 0; s < 7; ++s)
        f[1 + s] = sv * cf[((s * OO + o) * CC + c) * 9 + tap];
    uint4 pk;
    pk.x = bfb(f[0]) | (bfb(f[1]) << 16);
    pk.y = bfb(f[2]) | (bfb(f[3]) << 16);
    pk.z = bfb(f[4]) | (bfb(f[5]) << 16);
    pk.w = bfb(f[6]) | (bfb(f[7]) << 16);
    int cb = c >> 2, cl = c & 3;
    wb[((cb * 9 + tap) * 4 + cl) * OO + o] = pk;
}

// ---------------- main implicit GEMM ----------------
__global__ __launch_bounds__(512, 2) void kan_mfma14(
    const float* __restrict__ x, const uint4* __restrict__ wb,
    float* __restrict__ out)
{
    // B/features: [buf][(cl*6 + row)*66 + col], 1584 granules/buf
    __shared__ uint4 Bt[2][1584];
    // A/weights substep tile: TRIPLE buffered, At[dh] holds (cb, dh)
    __shared__ uint4 At[3][1536];

    const int tid  = threadIdx.x;
    const int blk  = blockIdx.x;
    const int hq   = blk & 15;
    const int b    = blk >> 4;
    const int h0   = hq << 2;          // output rows h0..h0+3; input rows h0-1..h0+4

    const int ww    = tid >> 6;        // wave 0..7
    const int lane  = tid & 63;
    const int lo    = lane & 31;
    const int hi    = lane >> 5;
    const int ohalf = ww & 1;
    const int hrow  = ww >> 1;         // 0..3

    f32x16 acc[2][2] = {};             // [oi][wi]
    float xv[4];
    uint4 pA[2][2], pB[2][2];          // persistent tl0 fragments (cross-barrier)

    // ---- x loads for channel-block cbi: 1584 granule-pixels (4cl x 6rows x 66) ----
    #define XLOAD(cbi) do {                                                   \
        _Pragma("unroll")                                                     \
        for (int k = 0; k < 4; ++k) {                                         \
            const int g = tid + k * 512;                                      \
            float v = 0.f;                                                    \
            if (g < 1584) {                                                   \
                const int cl_ = g / 396;                                      \
                const int r_  = (g % 396) / 66;                               \
                const int co_ = g % 66;                                       \
                const int hx  = h0 - 1 + r_;                                  \
                const int wx  = co_ - 1;                                      \
                if ((unsigned)hx < 64u && (unsigned)wx < 64u)                 \
                    v = x[((b * CC + (cbi) * 4 + cl_) * HH + hx) * WW + wx];  \
            }                                                                 \
            xv[k] = v;                                                        \
        }                                                                     \
    } while (0)

    // ---- feature compute + LDS write into Bt[bufi] ----
    #define FEATW(bufi) do {                                                  \
        _Pragma("unroll")                                                     \
        for (int k = 0; k < 4; ++k) {                                         \
            const int g = tid + k * 512;                                      \
            if (g < 1584) Bt[bufi][g] = feat_granule(xv[k]);                  \
        }                                                                     \
    } while (0)

    // ---- DMA one A substep slice (cb1, dh1) into At[bufi]: 24 x 1KB, 3/wave ----
    #define ADMA(bufi, cb1, dh1) do {                                         \
        const uint4* asrc = wb + ((cb1) * 4608 + (dh1) * 1536)                \
                            + ww * 192 + lane;                                \
        _Pragma("unroll")                                                     \
        for (int i = 0; i < 3; ++i)                                           \
            __builtin_amdgcn_global_load_lds(                                 \
                (const __attribute__((address_space(1))) void*)(asrc + i*64), \
                (__attribute__((address_space(3))) void*)                     \
                    &At[bufi][ww * 192 + i * 64],                             \
                16, 0, 0);                                                    \
    } while (0)

    #define READ_A(dst, Ab, tl) do {                                          \
        _Pragma("unroll")                                                     \
        for (int kh = 0; kh < 2; ++kh) {                                      \
            const int arow = ((tl) * 4 + kh * 2 + hi) * 128 + ohalf * 64 + lo;\
            dst[kh][0] = (Ab)[arow];                                          \
            dst[kh][1] = (Ab)[arow + 32];                                     \
        }                                                                     \
    } while (0)

    #define READ_B(dst, Bb, dhv, tl) do {                                     \
        _Pragma("unroll")                                                     \
        for (int kh = 0; kh < 2; ++kh) {                                      \
            const int brow = ((kh * 2 + hi) * 6 + hrow + (dhv)) * 66          \
                             + (tl) + lo;                                     \
            dst[kh][0] = (Bb)[brow];                                          \
            dst[kh][1] = (Bb)[brow + 32];                                     \
        }                                                                     \
    } while (0)

    // 8 MFMAs per tap-column — no setprio (R15/R16: it fences the scheduler)
    #define MFMA8(A_, B_) do {                                                \
        _Pragma("unroll")                                                     \
        for (int oi = 0; oi < 2; ++oi)                                        \
            _Pragma("unroll")                                                 \
            for (int wi = 0; wi < 2; ++wi)                                    \
                _Pragma("unroll")                                             \
                for (int kh = 0; kh < 2; ++kh)                                \
                    acc[oi][wi] = __builtin_amdgcn_mfma_f32_32x32x16_bf16(    \
                        as_bf16x8(A_[kh][oi]), as_bf16x8(B_[kh][wi]),         \
                        acc[oi][wi], 0, 0, 0);                                \
    } while (0)

    // prologue: Bt[0] <- features(cb0); At[0] <- (0,0); At[1] <- (0,1); full drain once
    XLOAD(0);
    ADMA(0, 0, 0);
    ADMA(1, 0, 1);
    FEATW(0);
    asm volatile("s_waitcnt vmcnt(0) lgkmcnt(0)" ::: "memory");
    __builtin_amdgcn_s_barrier();
    __builtin_amdgcn_sched_barrier(0);
    READ_A(pA, At[0], 0);              // tl0 A for substep 0 (B refilled in dh0 path)

    #pragma unroll 1
    for (int cb = 0; cb < 16; ++cb) {
        const uint4* Bb = Bt[cb & 1];

        #pragma unroll
        for (int dh = 0; dh < 3; ++dh) {
            // substep s = cb*3+dh reads At[dh] + pre-read slot At[(dh+1)%3]
            if (dh == 0) {
                READ_B(pB, Bb, 0, 0);          // tl0 B (couldn't pre-read across cb)
                ADMA(2, cb, 2);
                __builtin_amdgcn_sched_barrier(0);   // pin ADMA before XLOAD in queue
                if (cb < 15) XLOAD(cb + 1);
            } else if (dh == 1) {
                if (cb < 15) ADMA(0, cb + 1, 0);
            } else {
                if (cb < 15) ADMA(1, cb + 1, 1);
            }

            const uint4* Ab = At[dh];

            // ---- tl0: fragments already in registers ----
            MFMA8(pA, pB);

            // ---- tl1 ----
            uint4 a1[2][2], b1[2][2];
            READ_A(a1, Ab, 1);
            READ_B(b1, Bb, dh, 1);
            MFMA8(a1, b1);

            // ---- tl2 + pre-reads for next substep's tl0 ----
            uint4 a2[2][2], b2[2][2];
            READ_A(a2, Ab, 2);
            READ_B(b2, Bb, dh, 2);
            if (!(cb == 15 && dh == 2)) {
                READ_A(pA, At[(dh + 1) % 3], 0);   // next slot landed (tight vmcnt)
            }
            if (dh < 2) READ_B(pB, Bb, dh + 1, 0); // same Bt buffer within cb
            MFMA8(a2, b2);

            if (dh == 2 && cb < 15) FEATW((cb + 1) & 1);  // publish next-cb features

            // ---- raw barrier with tightened counted waits (R12-proven) ----
            if (!(cb == 15 && dh == 2)) {
                if (dh == 0) {
                    if (cb < 15) asm volatile("s_waitcnt vmcnt(4)" ::: "memory");
                    else         asm volatile("s_waitcnt vmcnt(0)" ::: "memory");
                } else if (dh == 1) {
                    asm volatile("s_waitcnt vmcnt(0)" ::: "memory");
                } else {
                    asm volatile("s_waitcnt vmcnt(0) lgkmcnt(0)" ::: "memory");
                }
                __builtin_amdgcn_s_barrier();
                __builtin_amdgcn_sched_barrier(0);
            }
        }
    }

    // ---- store: w-coalesced dword stores ----
    const int h = h0 + hrow;
    #pragma unroll
    for (int oi = 0; oi < 2; ++oi)
        #pragma unroll
        for (int wi = 0; wi < 2; ++wi) {
            const int wc = wi * 32 + lo;
            #pragma unroll
            for (int r = 0; r < 16; ++r) {
                const int o = ohalf * 64 + oi * 32 + (r & 3) + ((r >> 2) << 3) + (hi << 2);
                out[((b * OO + o) * HH + h) * WW + wc] = acc[oi][wi][r];
            }
        }
}

extern "C" void kernel_launch(void* const* d_in, const int* in_sizes, int n_in,
                              void* d_out, int out_size, void* d_ws, size_t ws_size,
                              hipStream_t stream) {
    const float* x    = (const float*)d_in[0];
    const float* beta = (const float*)d_in[1];
    const float* spl  = (const float*)d_in[2];
    const float* cf   = (const float*)d_in[3];
    float* out = (float*)d_out;
    uint4* wb  = (uint4*)d_ws;          // 73728 granules = 1.18 MB

    kan_wprep<<<288, 256, 0, stream>>>(beta, spl, cf, wb);
    kan_mfma14<<<BB * 16, 512, 0, stream>>>(x, wb, out);
}

// Round 18
// 83.571 us; speedup vs baseline: 1.1550x; 1.0052x over previous
//
#include <hip/hip_runtime.h>

// KANConv2d, round 18: K-split waves (4 hrow x 2 khalf), 4x2 fragment tile per wave.
// Cuts LDS reads/MFMA from 1.0 to 0.75 (per-CU port floor 54us -> 42us) while
// keeping 8 waves (2/SIMD) and R12's proven DMA/barrier/pre-read schedule intact.
// Each wave computes all 128o x 64w x 1h but only channels cl = khalf*2 + hi of
// each K-chunk; khalf partials are reduced through (dead) At LDS at the end.
//
// out[b,o,h,w] = sum_{c,tap,j} Wc[o,c,tap,j] * f_j(xp[b,c,h+dh,w+dw])
// f = {silu(v), B_0..B_6(v)} cardinal cubic B-splines (t = 2v+5), 8 bf16/granule.

#define BB 16
#define CC 64
#define HH 64
#define WW 64
#define OO 128

typedef __bf16 bf16x8 __attribute__((ext_vector_type(8)));
typedef float f32x16 __attribute__((ext_vector_type(16)));

__device__ __forceinline__ bf16x8 as_bf16x8(uint4 v) { return __builtin_bit_cast(bf16x8, v); }
__device__ __forceinline__ unsigned bfb(float f) {
    return (unsigned)__builtin_bit_cast(unsigned short, (__bf16)f);
}

// 8-feature granule {silu(v), B_0(v)..B_6(v)} packed as 8 bf16 via 128-bit shift scatter.
__device__ __forceinline__ uint4 feat_granule(float v) {
    const float silu = __fdividef(v, 1.f + __expf(-v));
    const float t  = fmaf(2.f, v, 5.f);
    const float fi = floorf(t);
    const float u  = t - fi;
    const float um = 1.f - u;
    const float u2 = u * u, u3 = u2 * u;
    const float k0 = um * um * um * (1.f / 6.f);
    const float k1 = fmaf(0.5f, u3, (2.f / 3.f) - u2);
    const float k2 = fmaf(-0.5f, u3, fmaf(0.5f, u2, fmaf(0.5f, u, 1.f / 6.f)));
    const float k3 = u3 * (1.f / 6.f);
    const bool valid = (t >= 0.f) && (t < 10.f);
    unsigned long long K =
        (unsigned long long)bfb(k0)         |
        ((unsigned long long)bfb(k1) << 16) |
        ((unsigned long long)bfb(k2) << 32) |
        ((unsigned long long)bfb(k3) << 48);
    if (!valid) K = 0ull;
    const int ic = min(max((int)fi, -2), 9);
    const int sh = 16 * ic - 32;            // [-64, 112]
    unsigned __int128 P = (sh >= 0) ? ((unsigned __int128)K << sh)
                                    : ((unsigned __int128)K >> (-sh));
    uint4 pk = __builtin_bit_cast(uint4, P);
    pk.x = (pk.x & 0xFFFF0000u) | bfb(silu);
    return pk;
}

// ---------------- weight prep: Wb[cb][tap][c_l][o][j] bf16, j contiguous ----------------
__global__ __launch_bounds__(256) void kan_wprep(
    const float* __restrict__ beta, const float* __restrict__ spl,
    const float* __restrict__ cf, uint4* __restrict__ wb)
{
    int t = blockIdx.x * 256 + threadIdx.x;      // 73728 = (o, c, tap)
    int tap = t % 9;
    int c   = (t / 9) & 63;
    int o   = t / 576;
    int base = (o * CC + c) * 9 + tap;
    float bv = beta[base];
    float sv = spl[base];
    float f[8];
    f[0] = bv;
    #pragma unroll
    for (int s = 0; s < 7; ++s)
        f[1 + s] = sv * cf[((s * OO + o) * CC + c) * 9 + tap];
    uint4 pk;
    pk.x = bfb(f[0]) | (bfb(f[1]) << 16);
    pk.y = bfb(f[2]) | (bfb(f[3]) << 16);
    pk.z = bfb(f[4]) | (bfb(f[5]) << 16);
    pk.w = bfb(f[6]) | (bfb(f[7]) << 16);
    int cb = c >> 2, cl = c & 3;
    wb[((cb * 9 + tap) * 4 + cl) * OO + o] = pk;
}

// ---------------- main implicit GEMM ----------------
__global__ __launch_bounds__(512, 2) void kan_mfma15(
    const float* __restrict__ x, const uint4* __restrict__ wb,
    float* __restrict__ out)
{
    // B/features: [buf][(cl*6 + row)*66 + col], 1584 granules/buf
    __shared__ uint4 Bt[2][1584];
    // A/weights substep tile: TRIPLE buffered, At[dh] holds (cb, dh)
    __shared__ uint4 At[3][1536];

    const int tid  = threadIdx.x;
    const int blk  = blockIdx.x;
    const int hq   = blk & 15;
    const int b    = blk >> 4;
    const int h0   = hq << 2;          // output rows h0..h0+3; input rows h0-1..h0+4

    const int ww    = tid >> 6;        // wave 0..7
    const int lane  = tid & 63;
    const int lo    = lane & 31;
    const int hi    = lane >> 5;
    const int hrow  = ww & 3;          // output row within quad
    const int khalf = ww >> 2;         // which half of each K-chunk (channel pair)
    const int clb   = khalf * 2 + hi;  // this wave-lane's channel-lane 0..3

    f32x16 acc[4][2] = {};             // [oi][wi] -- K-half partials
    float xv[4];
    uint4 pA[4], pB[2];                // persistent tl0 fragments (cross-barrier)

    // ---- x loads for channel-block cbi: 1584 granule-pixels (4cl x 6rows x 66) ----
    #define XLOAD(cbi) do {                                                   \
        _Pragma("unroll")                                                     \
        for (int k = 0; k < 4; ++k) {                                         \
            const int g = tid + k * 512;                                      \
            float v = 0.f;                                                    \
            if (g < 1584) {                                                   \
                const int cl_ = g / 396;                                      \
                const int r_  = (g % 396) / 66;                               \
                const int co_ = g % 66;                                       \
                const int hx  = h0 - 1 + r_;                                  \
                const int wx  = co_ - 1;                                      \
                if ((unsigned)hx < 64u && (unsigned)wx < 64u)                 \
                    v = x[((b * CC + (cbi) * 4 + cl_) * HH + hx) * WW + wx];  \
            }                                                                 \
            xv[k] = v;                                                        \
        }                                                                     \
    } while (0)

    // ---- feature compute + LDS write into Bt[bufi] ----
    #define FEATW(bufi) do {                                                  \
        _Pragma("unroll")                                                     \
        for (int k = 0; k < 4; ++k) {                                         \
            const int g = tid + k * 512;                                      \
            if (g < 1584) Bt[bufi][g] = feat_granule(xv[k]);                  \
        }                                                                     \
    } while (0)

    // ---- DMA one A substep slice (cb1, dh1) into At[bufi]: 24 x 1KB, 3/wave ----
    #define ADMA(bufi, cb1, dh1) do {                                         \
        const uint4* asrc = wb + ((cb1) * 4608 + (dh1) * 1536)                \
                            + ww * 192 + lane;                                \
        _Pragma("unroll")                                                     \
        for (int i = 0; i < 3; ++i)                                           \
            __builtin_amdgcn_global_load_lds(                                 \
                (const __attribute__((address_space(1))) void*)(asrc + i*64), \
                (__attribute__((address_space(3))) void*)                     \
                    &At[bufi][ww * 192 + i * 64],                             \
                16, 0, 0);                                                    \
    } while (0)

    // ---- A fragments (4 oi) of one tap-column for this wave's channel-lane ----
    #define READ_A4(dst, Ab, tl) do {                                         \
        _Pragma("unroll")                                                     \
        for (int oi = 0; oi < 4; ++oi)                                        \
            dst[oi] = (Ab)[((tl) * 4 + clb) * 128 + oi * 32 + lo];            \
    } while (0)

    // ---- B fragments (2 wi) of one tap-column ----
    #define READ_B2(dst, Bb, dhv, tl) do {                                    \
        const int brow_ = (clb * 6 + hrow + (dhv)) * 66 + (tl) + lo;          \
        dst[0] = (Bb)[brow_];                                                 \
        dst[1] = (Bb)[brow_ + 32];                                            \
    } while (0)

    // ---- one tap-column: 8 MFMAs (4 oi x 2 wi), single K-half ----
    #define MFMA8K(A_, B_) do {                                               \
        __builtin_amdgcn_s_setprio(1);                                        \
        _Pragma("unroll")                                                     \
        for (int oi = 0; oi < 4; ++oi)                                        \
            _Pragma("unroll")                                                 \
            for (int wi = 0; wi < 2; ++wi)                                    \
                acc[oi][wi] = __builtin_amdgcn_mfma_f32_32x32x16_bf16(        \
                    as_bf16x8(A_[oi]), as_bf16x8(B_[wi]),                     \
                    acc[oi][wi], 0, 0, 0);                                    \
        __builtin_amdgcn_s_setprio(0);                                        \
    } while (0)

    // prologue: Bt[0] <- features(cb0); At[0] <- (0,0); At[1] <- (0,1); full drain once
    XLOAD(0);
    ADMA(0, 0, 0);
    ADMA(1, 0, 1);
    FEATW(0);
    asm volatile("s_waitcnt vmcnt(0) lgkmcnt(0)" ::: "memory");
    __builtin_amdgcn_s_barrier();
    __builtin_amdgcn_sched_barrier(0);
    READ_A4(pA, At[0], 0);             // tl0 A for substep 0 (B refilled in dh0 path)

    #pragma unroll 1
    for (int cb = 0; cb < 16; ++cb) {
        const uint4* Bb = Bt[cb & 1];

        #pragma unroll
        for (int dh = 0; dh < 3; ++dh) {
            // substep s = cb*3+dh reads At[dh] + pre-read slot At[(dh+1)%3]
            if (dh == 0) {
                READ_B2(pB, Bb, 0, 0);         // tl0 B (couldn't pre-read across cb)
                ADMA(2, cb, 2);
                __builtin_amdgcn_sched_barrier(0);   // pin ADMA before XLOAD in queue
                if (cb < 15) XLOAD(cb + 1);
            } else if (dh == 1) {
                if (cb < 15) ADMA(0, cb + 1, 0);
            } else {
                if (cb < 15) ADMA(1, cb + 1, 1);
            }

            const uint4* Ab = At[dh];

            // ---- tl0: fragments already in registers ----
            MFMA8K(pA, pB);

            // ---- tl1 ----
            uint4 a1[4], b1[2];
            READ_A4(a1, Ab, 1);
            READ_B2(b1, Bb, dh, 1);
            MFMA8K(a1, b1);

            // ---- tl2 + pre-reads for next substep's tl0 ----
            uint4 a2[4], b2[2];
            READ_A4(a2, Ab, 2);
            READ_B2(b2, Bb, dh, 2);
            if (!(cb == 15 && dh == 2)) {
                READ_A4(pA, At[(dh + 1) % 3], 0);  // next slot landed (tight vmcnt)
            }
            if (dh < 2) READ_B2(pB, Bb, dh + 1, 0); // same Bt buffer within cb
            MFMA8K(a2, b2);

            if (dh == 2 && cb < 15) FEATW((cb + 1) & 1);  // publish next-cb features

            // ---- raw barrier with counted waits (R12-proven; VMEM seq identical) ----
            if (!(cb == 15 && dh == 2)) {
                if (dh == 0) {
                    if (cb < 15) asm volatile("s_waitcnt vmcnt(4)" ::: "memory");
                    else         asm volatile("s_waitcnt vmcnt(0)" ::: "memory");
                } else if (dh == 1) {
                    asm volatile("s_waitcnt vmcnt(0)" ::: "memory");
                } else {
                    asm volatile("s_waitcnt vmcnt(0) lgkmcnt(0)" ::: "memory");
                }
                __builtin_amdgcn_s_barrier();
                __builtin_amdgcn_sched_barrier(0);
            }
        }
    }

    // ---- K-half reduction through (dead) At space: 2 rounds of 64KB ----
    float* red = (float*)&At[0][0];    // 73.7KB available; round uses 64KB
    #pragma unroll
    for (int rr = 0; rr < 2; ++rr) {
        __syncthreads();               // main-loop At[2] reads done / prev round done
        if (khalf == 1) {
            #pragma unroll
            for (int oi2 = 0; oi2 < 2; ++oi2)
                #pragma unroll
                for (int wi = 0; wi < 2; ++wi) {
                    const f32x16 v = acc[rr * 2 + oi2][wi];
                    const int slot = hrow * 4 + oi2 * 2 + wi;     // 0..15
                    float4* d4 = (float4*)red + slot * 256 + lane * 4;
                    d4[0] = make_float4(v[0],  v[1],  v[2],  v[3]);
                    d4[1] = make_float4(v[4],  v[5],  v[6],  v[7]);
                    d4[2] = make_float4(v[8],  v[9],  v[10], v[11]);
                    d4[3] = make_float4(v[12], v[13], v[14], v[15]);
                }
        }
        __syncthreads();
        if (khalf == 0) {
            #pragma unroll
            for (int oi2 = 0; oi2 < 2; ++oi2)
                #pragma unroll
                for (int wi = 0; wi < 2; ++wi) {
                    const int slot = hrow * 4 + oi2 * 2 + wi;
                    const float4* s4 = (const float4*)red + slot * 256 + lane * 4;
                    float4 r0 = s4[0], r1 = s4[1], r2 = s4[2], r3 = s4[3];
                    f32x16& a = acc[rr * 2 + oi2][wi];
                    a[0]  += r0.x; a[1]  += r0.y; a[2]  += r0.z; a[3]  += r0.w;
                    a[4]  += r1.x; a[5]  += r1.y; a[6]  += r1.z; a[7]  += r1.w;
                    a[8]  += r2.x; a[9]  += r2.y; a[10] += r2.z; a[11] += r2.w;
                    a[12] += r3.x; a[13] += r3.y; a[14] += r3.z; a[15] += r3.w;
                }
        }
    }

    // ---- store (khalf==0 waves only): w-coalesced dword stores ----
    if (khalf == 0) {
        const int h = h0 + hrow;
        #pragma unroll
        for (int oi = 0; oi < 4; ++oi)
            #pragma unroll
            for (int wi = 0; wi < 2; ++wi) {
                const int wc = wi * 32 + lo;
                #pragma unroll
                for (int r = 0; r < 16; ++r) {
                    const int o = oi * 32 + (r & 3) + ((r >> 2) << 3) + (hi << 2);
                    out[((b * OO + o) * HH + h) * WW + wc] = acc[oi][wi][r];
                }
            }
    }
}

extern "C" void kernel_launch(void* const* d_in, const int* in_sizes, int n_in,
                              void* d_out, int out_size, void* d_ws, size_t ws_size,
                              hipStream_t stream) {
    const float* x    = (const float*)d_in[0];
    const float* beta = (const float*)d_in[1];
    const float* spl  = (const float*)d_in[2];
    const float* cf   = (const float*)d_in[3];
    float* out = (float*)d_out;
    uint4* wb  = (uint4*)d_ws;          // 73728 granules = 1.18 MB

    kan_wprep<<<288, 256, 0, stream>>>(beta, spl, cf, wb);
    kan_mfma15<<<BB * 16, 512, 0, stream>>>(x, wb, out);
}